// Round 7
// baseline (181.155 us; speedup 1.0000x reference)
//
#include <hip/hip_runtime.h>
#include <hip/hip_fp16.h>

#define NTOT   6422528   // 16*56*56*128
#define NPERB  401408    // 56*56*128
#define NQ4    100352    // NPERB/4
#define LOG2E  1.4426950408889634f

__device__ __forceinline__ float sigmoidf_fast(float x) {
    return __builtin_amdgcn_rcpf(1.f + __expf(-x));
}

__device__ __forceinline__ void kappa_consts(const float* kap, float* dcs) {
    float v[5]; float mean = 0.f;
    for (int s = 0; s < 5; s++) {
        float lr = 0.6931471805599453f * (float)(s + 1);
        float k_ = 1.f / (1.f + expf(-kap[s]));
        float lk = 1.f / (1.f + expf(-logf(k_ + 1e-7f)));
        v[s] = lk + lr; mean += v[s];
    }
    mean *= 0.2f; float nd = 0.f;
    for (int s = 0; s < 5; s++) { float d = v[s] - mean; dcs[s] = d; nd += d * d; }
    dcs[5] = sqrtf(nd);
}

struct ScaleU { int rb1, rb0; float xmch; };

// ---------- K0: per-sample min/max partials (slot-per-block, no atomics) ----------
// 1024 blocks x 256: b = p&15 (XCD b%8), chunk = p>>4 in [0,64).
// chunk==0 blocks also zero sq (safe: stream-ordered before k_satg).
__global__ void k_minmax(const float4* __restrict__ x4,
                         float* __restrict__ pmxp, float* __restrict__ pmnp,
                         float* __restrict__ sq) {
    int p = blockIdx.x;
    int b = p & 15, chunk = p >> 4;
    if (chunk == 0) {
        for (int k = threadIdx.x; k < 128; k += 256) sq[b * 128 + k] = 0.f;
    }
    const float4* base = x4 + b * NQ4 + chunk * 1568;
    float mx = -3.4e38f, mn = 3.4e38f;
    for (int q = threadIdx.x; q < 1568; q += 256) {
        float4 v = base[q];
        mx = fmaxf(mx, fmaxf(fmaxf(v.x, v.y), fmaxf(v.z, v.w)));
        mn = fminf(mn, fminf(fminf(v.x, v.y), fminf(v.z, v.w)));
    }
    __shared__ float rmx[4], rmn[4];
    int lane = threadIdx.x & 63, w = threadIdx.x >> 6;
#pragma unroll
    for (int off = 32; off; off >>= 1) {
        mx = fmaxf(mx, __shfl_down(mx, off));
        mn = fminf(mn, __shfl_down(mn, off));
    }
    if (lane == 0) { rmx[w] = mx; rmn[w] = mn; }
    __syncthreads();
    if (threadIdx.x == 0) {
        mx = fmaxf(fmaxf(rmx[0], rmx[1]), fmaxf(rmx[2], rmx[3]));
        mn = fminf(fminf(rmn[0], rmn[1]), fminf(rmn[2], rmn[3]));
        pmxp[b * 64 + chunk] = mx;
        pmnp[b * 64 + chunk] = mn;
    }
}

// ---------- K1: SAT-in-LDS (channel-pair float2) + gather ----------
// 1024 blocks x 448 threads. b = p&15 (XCD b%8), cg = p>>4 in [0,64),
// channels {cg*2, cg*2+1}. SAT2[57*57] float2 = 26KB -> 4 blocks/CU, 28 waves.
// Thread t: pos = t%56, seg = t/56 in [0,8); each thread: 7 pixels x 2 channels.
__launch_bounds__(448, 7)
__global__ void k_satg(const float* __restrict__ x,   const float* __restrict__ kap,
                       const float* __restrict__ gam, const float* __restrict__ bet,
                       const float* __restrict__ bnm, const float* __restrict__ bnv,
                       const float* __restrict__ pmxp, const float* __restrict__ pmnp,
                       float* __restrict__ sq, unsigned int* __restrict__ ABu) {
    __shared__ float2 SAT2[57 * 57];   // [row*57 + col], 25992 B
    __shared__ float2 tot2[448];
    __shared__ float  wsum[14];        // [wave][cc]
    __shared__ float  cst[9];          // d0..d4, nd, xm, xi, xm*xi

    const int p = blockIdx.x;
    const int b = p & 15, cg = p >> 4;
    const int c0 = cg * 2;
    const int t = threadIdx.x;
    const int pos = t % 56;
    const int seg = t / 56;            // [0,8)

    // guards: SAT row 0 (cols 0..56) and col 0 (rows 1..56)
    if (t < 57) SAT2[t] = make_float2(0.f, 0.f);
    if (t >= 64 && t < 120) SAT2[(t - 63) * 57] = make_float2(0.f, 0.f);
    if (t == 128) {
        float d[6]; kappa_consts(kap, d);
#pragma unroll
        for (int s2 = 0; s2 < 6; s2++) cst[s2] = d[s2];
    }

    float2 v[7];
    // ---- A1: column prefix along i (8-way segmented); pos=j, seg=i-seg ----
    {
        const float2* xp = (const float2*)(x + b * NPERB + seg * 7 * 7168 + pos * 128 + c0);
        float2 acc = make_float2(0.f, 0.f);
#pragma unroll
        for (int k = 0; k < 7; k++) {
            float2 xv = xp[k * 3584];
            acc.x += xv.x; acc.y += xv.y;
            v[k] = acc;
        }
        tot2[t] = acc;
    }
    __syncthreads();   // S1
    // wave 0 reduces the 64 min/max partial slots while others write SAT
    if (t < 64) {
        float mxv = pmxp[b * 64 + t];
        float mnv = pmnp[b * 64 + t];
#pragma unroll
        for (int off = 32; off; off >>= 1) {
            mxv = fmaxf(mxv, __shfl_down(mxv, off));
            mnv = fminf(mnv, __shfl_down(mnv, off));
        }
        if (t == 0) {
            float xi = 1.f / (mxv - mnv + 1e-7f);
            cst[6] = mnv; cst[7] = xi; cst[8] = mnv * xi;
        }
    }
    {
        float2 base = make_float2(0.f, 0.f);
        for (int s = 0; s < seg; s++) {
            float2 tv = tot2[s * 56 + pos];
            base.x += tv.x; base.y += tv.y;
        }
#pragma unroll
        for (int k = 0; k < 7; k++)
            SAT2[(seg * 7 + 1 + k) * 57 + (pos + 1)] =
                make_float2(base.x + v[k].x, base.y + v[k].y);
    }
    __syncthreads();   // S2: column-prefix SAT complete

    // ---- A2: row prefix along j, in place; pos=i, seg=j-seg ----
    {
        const int rbase = (pos + 1) * 57 + seg * 7 + 1;
#pragma unroll
        for (int k = 0; k < 7; k++) v[k] = SAT2[rbase + k];
#pragma unroll
        for (int k = 1; k < 7; k++) { v[k].x += v[k - 1].x; v[k].y += v[k - 1].y; }
        tot2[seg * 56 + pos] = v[6];
    }
    __syncthreads();   // S3
    {
        float2 base = make_float2(0.f, 0.f);
        for (int s = 0; s < seg; s++) {
            float2 tv = tot2[s * 56 + pos];
            base.x += tv.x; base.y += tv.y;
        }
        const int rbase = (pos + 1) * 57 + seg * 7 + 1;
#pragma unroll
        for (int k = 0; k < 7; k++)
            SAT2[rbase + k] = make_float2(base.x + v[k].x, base.y + v[k].y);
    }
    __syncthreads();   // S4: full SAT + cst ready

    // ---- A3: gather 7 pixels x 2 channels -> pack A/B -> ABu + squeeze ----
    float asx = 0.f, asy = 0.f;
    {
        const int i = pos;
        const int j0 = seg * 7;
        const float xm = cst[6], xi = cst[7], xmxi = cst[8];
        const float d0 = cst[0], d1 = cst[1], d2 = cst[2], d3 = cst[3], d4 = cst[4], nd = cst[5];
        float C1x, C0x, C1y, C0y;
        {
            float g = gam[c0], be = bet[c0], bm = bnm[c0];
            float rsv = rsqrtf(bnv[c0] + 1e-3f);
            C1x = -(g * rsv) * (LOG2E * 0.1f);
            C0x = -(be - g * bm * rsv) * LOG2E;
            g = gam[c0 + 1]; be = bet[c0 + 1]; bm = bnm[c0 + 1];
            rsv = rsqrtf(bnv[c0 + 1] + 1e-3f);
            C1y = -(g * rsv) * (LOG2E * 0.1f);
            C0y = -(be - g * bm * rsv) * LOG2E;
        }

        auto mkU = [&](int hk) {
            ScaleU uu;
            int y1g = min(i + hk, 55) + 1;
            int y0g = max(i - hk + 1, 0);
            uu.rb1 = y1g * 57; uu.rb0 = y0g * 57;
            uu.xmch = xm * (float)(y1g - y0g);
            return uu;
        };
        const ScaleU u0 = mkU(1), u1 = mkU(2), u2 = mkU(4), u3 = mkU(8), u4 = mkU(16);

        auto meas = [&](int j, const ScaleU& uu, int hk) -> float2 {
            int x1g = min(j + hk, 55) + 1;
            int x0g = max(j - hk + 1, 0);
            float cw = (float)(x1g - x0g);
            float2 a = SAT2[uu.rb1 + x1g], bq = SAT2[uu.rb0 + x1g];
            float2 cq = SAT2[uu.rb1 + x0g], dq = SAT2[uu.rb0 + x0g];
            float sx = a.x - bq.x - cq.x + dq.x;
            float sy = a.y - bq.y - cq.y + dq.y;
            float tx = fmaf(-uu.xmch, cw, sx);
            float ty = fmaf(-uu.xmch, cw, sy);
            float2 r;
            r.x = __log2f(fmaxf(fmaf(tx, xi, 1e-7f), 1e-7f));
            r.y = __log2f(fmaxf(fmaf(ty, xi, 1e-7f), 1e-7f));
            return r;
        };

        const float2* xrow = (const float2*)(x + b * NPERB + i * 7168 + c0);
        uint2* abrow = (uint2*)(ABu + b * NPERB + i * 7168 + c0);

        // hoisted x loads: 7-deep MLP, one wait
        float2 xv[7];
#pragma unroll
        for (int k = 0; k < 7; k++) xv[k] = xrow[(j0 + k) * 64];

#pragma unroll
        for (int jj = 0; jj < 7; jj++) {
            int j = j0 + jj;
            float2 l0 = meas(j, u0, 1);
            float2 l1 = meas(j, u1, 2);
            float2 l2 = meas(j, u2, 4);
            float2 l3 = meas(j, u3, 8);
            float2 l4 = meas(j, u4, 16);
            uint2 outw;
            {
                float w2 = -2.f * l0.x - l1.x + l3.x + 2.f * l4.x;
                asx += w2;
                float alphas = w2 * 0.1f;
                float mean = 0.2f * (l0.x + l1.x + l2.x + l3.x + l4.x);
                float a0 = l0.x - mean, a1 = l1.x - mean, a2 = l2.x - mean,
                      a3 = l3.x - mean, a4 = l4.x - mean;
                float na2  = a0 * a0 + a1 * a1 + a2 * a2 + a3 * a3 + a4 * a4;
                float adot = a0 * d0 + a1 * d1 + a2 * d2 + a3 * d3 + a4 * d4;
                float na = __builtin_amdgcn_sqrtf(na2);
                float cosv = (alphas * adot) *
                             __builtin_amdgcn_rcpf(na * fabsf(alphas) * nd + 1e-7f);
                float sim = 0.5f * (cosv + 1.f);
                float sbn = __builtin_amdgcn_rcpf(1.f + exp2f(C1x * w2 + C0x));
                float xs = fmaf(xv[jj].x, xi, -xmxi);
                outw.x = __builtin_bit_cast(unsigned int,
                          __floats2half2_rn(sim * sbn, (1.f - sim) * xs));
            }
            {
                float w2 = -2.f * l0.y - l1.y + l3.y + 2.f * l4.y;
                asy += w2;
                float alphas = w2 * 0.1f;
                float mean = 0.2f * (l0.y + l1.y + l2.y + l3.y + l4.y);
                float a0 = l0.y - mean, a1 = l1.y - mean, a2 = l2.y - mean,
                      a3 = l3.y - mean, a4 = l4.y - mean;
                float na2  = a0 * a0 + a1 * a1 + a2 * a2 + a3 * a3 + a4 * a4;
                float adot = a0 * d0 + a1 * d1 + a2 * d2 + a3 * d3 + a4 * d4;
                float na = __builtin_amdgcn_sqrtf(na2);
                float cosv = (alphas * adot) *
                             __builtin_amdgcn_rcpf(na * fabsf(alphas) * nd + 1e-7f);
                float sim = 0.5f * (cosv + 1.f);
                float sbn = __builtin_amdgcn_rcpf(1.f + exp2f(C1y * w2 + C0y));
                float xs = fmaf(xv[jj].y, xi, -xmxi);
                outw.y = __builtin_bit_cast(unsigned int,
                          __floats2half2_rn(sim * sbn, (1.f - sim) * xs));
            }
            abrow[j * 64] = outw;
        }
    }
    // squeeze: wave reduce both channels, then cross-wave via LDS
#pragma unroll
    for (int off = 32; off; off >>= 1) {
        asx += __shfl_down(asx, off);
        asy += __shfl_down(asy, off);
    }
    if ((t & 63) == 0) { wsum[(t >> 6) * 2] = asx; wsum[(t >> 6) * 2 + 1] = asy; }
    __syncthreads();
    if (t < 2) {
        float s = 0.f;
#pragma unroll
        for (int w = 0; w < 7; w++) s += wsum[w * 2 + t];
        atomicAdd(&sq[b * 128 + c0 + t], s * 0.1f);
    }
}

// ---------- K2: SE + mix (XCD-affine: b = p&15, ABu read is L2-local) ----------
__launch_bounds__(256)
__global__ void k_mix(const unsigned int* __restrict__ ABu, const float* __restrict__ sq,
                      const float* __restrict__ W1, const float* __restrict__ b1,
                      const float* __restrict__ W2, const float* __restrict__ b2,
                      float* __restrict__ out) {
    __shared__ float sqz[128];
    __shared__ float hidp[256];
    __shared__ float hid[16];
    __shared__ float exc[128];
    int p = blockIdx.x;
    int b = p & 15, chunk = p >> 4;
    int tid = threadIdx.x;
    if (tid < 128) sqz[tid] = sq[b * 128 + tid] * (1.f / 3136.f);
    __syncthreads();
    {   // W1 GEMV parallel: h = tid&15, c2 group = tid>>4 (8 c2 each)
        int h = tid & 15, g = tid >> 4;
        float acc = 0.f;
#pragma unroll
        for (int k = 0; k < 8; k++) {
            int c2 = g * 8 + k;
            acc += sqz[c2] * W1[c2 * 16 + h];
        }
        hidp[tid] = acc;
    }
    __syncthreads();
    if (tid < 16) {
        float acc = b1[tid];
#pragma unroll
        for (int g = 0; g < 16; g++) acc += hidp[g * 16 + tid];
        hid[tid] = fmaxf(acc, 0.f);
    }
    __syncthreads();
    if (tid < 128) {
        float acc = b2[tid];
#pragma unroll
        for (int h = 0; h < 16; h++) acc += hid[h] * W2[h * 128 + tid];
        exc[tid] = sigmoidf_fast(acc);
    }
    __syncthreads();
    const uint4* ab4 = (const uint4*)ABu + b * NQ4 + chunk * 784;
    float4* out4 = (float4*)out + b * NQ4 + chunk * 784;
    for (int q = tid; q < 784; q += 256) {
        int cb = ((chunk * 784 + q) & 31) << 2;
        uint4 u = ab4[q];
        float2 p0 = __half22float2(__builtin_bit_cast(__half2, u.x));
        float2 p1 = __half22float2(__builtin_bit_cast(__half2, u.y));
        float2 p2 = __half22float2(__builtin_bit_cast(__half2, u.z));
        float2 p3 = __half22float2(__builtin_bit_cast(__half2, u.w));
        out4[q] = make_float4(p0.x + p0.y * exc[cb],
                              p1.x + p1.y * exc[cb + 1],
                              p2.x + p2.y * exc[cb + 2],
                              p3.x + p3.y * exc[cb + 3]);
    }
}

extern "C" void kernel_launch(void* const* d_in, const int* in_sizes, int n_in,
                              void* d_out, int out_size, void* d_ws, size_t ws_size,
                              hipStream_t stream) {
    const float* x   = (const float*)d_in[0];
    const float* kap = (const float*)d_in[1];
    const float* W1  = (const float*)d_in[2];
    const float* b1  = (const float*)d_in[3];
    const float* W2  = (const float*)d_in[4];
    const float* b2  = (const float*)d_in[5];
    const float* gam = (const float*)d_in[6];
    const float* bet = (const float*)d_in[7];
    const float* bnm = (const float*)d_in[8];
    const float* bnv = (const float*)d_in[9];
    float* out = (float*)d_out;

    // ws: [sq 2048f][pmxp 1024f][pmnp 1024f][ABu NTOT u32]  (no memset needed:
    // sq zeroed by k_minmax chunk-0 blocks; pmxp/pmnp fully written per slot)
    float* sq   = (float*)d_ws;
    float* pmxp = sq + 2048;
    float* pmnp = pmxp + 1024;
    unsigned* ABu = (unsigned*)(pmnp + 1024);   // byte offset 16384, 16B aligned

    k_minmax<<<1024, 256, 0, stream>>>((const float4*)x, pmxp, pmnp, sq);
    k_satg<<<1024, 448, 0, stream>>>(x, kap, gam, bet, bnm, bnv, pmxp, pmnp, sq, ABu);
    k_mix<<<2048, 256, 0, stream>>>(ABu, sq, W1, b1, W2, b2, out);
}

// Round 8
// 143.113 us; speedup vs baseline: 1.2658x; 1.2658x over previous
//
#include <hip/hip_runtime.h>
#include <hip/hip_fp16.h>

#define NTOT   6422528   // 16*56*56*128
#define NPERB  401408    // 56*56*128
#define NQ4    100352    // NPERB/4
#define LOG2E  1.4426950408889634f

__device__ __forceinline__ float sigmoidf_fast(float x) {
    return __builtin_amdgcn_rcpf(1.f + __expf(-x));
}

__device__ __forceinline__ void kappa_consts(const float* kap, float* dcs) {
    float v[5]; float mean = 0.f;
    for (int s = 0; s < 5; s++) {
        float lr = 0.6931471805599453f * (float)(s + 1);
        float k_ = 1.f / (1.f + expf(-kap[s]));
        float lk = 1.f / (1.f + expf(-logf(k_ + 1e-7f)));
        v[s] = lk + lr; mean += v[s];
    }
    mean *= 0.2f; float nd = 0.f;
    for (int s = 0; s < 5; s++) { float d = v[s] - mean; dcs[s] = d; nd += d * d; }
    dcs[5] = sqrtf(nd);
}

struct ScaleU { int rb1, rb0; float xmch; };

// ---------- K0: per-sample min/max partials (slot-per-block, no atomics) ----------
// 1024 blocks x 256: b = p&15 (XCD b%8), chunk = p>>4 in [0,64).
// chunk==0 blocks also zero sq (stream-ordered before k_satg).
__global__ void k_minmax(const float4* __restrict__ x4,
                         float* __restrict__ pmxp, float* __restrict__ pmnp,
                         float* __restrict__ sq) {
    int p = blockIdx.x;
    int b = p & 15, chunk = p >> 4;
    if (chunk == 0) {
        for (int k = threadIdx.x; k < 128; k += 256) sq[b * 128 + k] = 0.f;
    }
    const float4* base = x4 + b * NQ4 + chunk * 1568;
    float mx = -3.4e38f, mn = 3.4e38f;
    for (int q = threadIdx.x; q < 1568; q += 256) {
        float4 v = base[q];
        mx = fmaxf(mx, fmaxf(fmaxf(v.x, v.y), fmaxf(v.z, v.w)));
        mn = fminf(mn, fminf(fminf(v.x, v.y), fminf(v.z, v.w)));
    }
    __shared__ float rmx[4], rmn[4];
    int lane = threadIdx.x & 63, w = threadIdx.x >> 6;
#pragma unroll
    for (int off = 32; off; off >>= 1) {
        mx = fmaxf(mx, __shfl_down(mx, off));
        mn = fminf(mn, __shfl_down(mn, off));
    }
    if (lane == 0) { rmx[w] = mx; rmn[w] = mn; }
    __syncthreads();
    if (threadIdx.x == 0) {
        mx = fmaxf(fmaxf(rmx[0], rmx[1]), fmaxf(rmx[2], rmx[3]));
        mn = fminf(fminf(rmn[0], rmn[1]), fminf(rmn[2], rmn[3]));
        pmxp[b * 64 + chunk] = mx;
        pmnp[b * 64 + chunk] = mn;
    }
}

// ---------- K1: SAT-in-LDS (channel-pair float2) + gather ----------
// 1024 blocks x 448 threads. b = p&15 (XCD b%8), cg = p>>4 in [0,64),
// channels {cg*2, cg*2+1}. SAT2[57*57] float2 = 26KB -> 4 blocks/CU, 28 waves.
// Thread t: pos = t%56, seg = t/56 in [0,8); each thread: 7 pixels x 2 channels.
__launch_bounds__(448, 7)
__global__ void k_satg(const float* __restrict__ x,   const float* __restrict__ kap,
                       const float* __restrict__ gam, const float* __restrict__ bet,
                       const float* __restrict__ bnm, const float* __restrict__ bnv,
                       const float* __restrict__ pmxp, const float* __restrict__ pmnp,
                       float* __restrict__ sq, unsigned int* __restrict__ ABu) {
    __shared__ float2 SAT2[57 * 57];   // [row*57 + col], 25992 B
    __shared__ float2 tot2[448];
    __shared__ float  wsum[14];        // [wave][cc]
    __shared__ float  cst[9];          // d0..d4, nd, xm, xi, xm*xi

    const int p = blockIdx.x;
    const int b = p & 15, cg = p >> 4;
    const int c0 = cg * 2;
    const int t = threadIdx.x;
    const int pos = t % 56;
    const int seg = t / 56;            // [0,8)

    // guards: SAT row 0 (cols 0..56) and col 0 (rows 1..56)
    if (t < 57) SAT2[t] = make_float2(0.f, 0.f);
    if (t >= 64 && t < 120) SAT2[(t - 63) * 57] = make_float2(0.f, 0.f);
    if (t == 128) {
        float d[6]; kappa_consts(kap, d);
#pragma unroll
        for (int s2 = 0; s2 < 6; s2++) cst[s2] = d[s2];
    }

    float2 v[7];
    // ---- A1: column prefix along i (8-way segmented); pos=j, seg=i-seg ----
    {
        const float2* xp = (const float2*)(x + b * NPERB + seg * 7 * 7168 + pos * 128 + c0);
        float2 acc = make_float2(0.f, 0.f);
#pragma unroll
        for (int k = 0; k < 7; k++) {
            float2 xv = xp[k * 3584];
            acc.x += xv.x; acc.y += xv.y;
            v[k] = acc;
        }
        tot2[t] = acc;
    }
    __syncthreads();   // S1
    // wave 0 reduces the 64 min/max partial slots while others write SAT
    if (t < 64) {
        float mxv = pmxp[b * 64 + t];
        float mnv = pmnp[b * 64 + t];
#pragma unroll
        for (int off = 32; off; off >>= 1) {
            mxv = fmaxf(mxv, __shfl_down(mxv, off));
            mnv = fminf(mnv, __shfl_down(mnv, off));
        }
        if (t == 0) {
            float xi = 1.f / (mxv - mnv + 1e-7f);
            cst[6] = mnv; cst[7] = xi; cst[8] = mnv * xi;
        }
    }
    {
        float2 base = make_float2(0.f, 0.f);
        for (int s = 0; s < seg; s++) {
            float2 tv = tot2[s * 56 + pos];
            base.x += tv.x; base.y += tv.y;
        }
#pragma unroll
        for (int k = 0; k < 7; k++)
            SAT2[(seg * 7 + 1 + k) * 57 + (pos + 1)] =
                make_float2(base.x + v[k].x, base.y + v[k].y);
    }
    __syncthreads();   // S2: column-prefix SAT complete

    // ---- A2: row prefix along j, in place; pos=i, seg=j-seg ----
    {
        const int rbase = (pos + 1) * 57 + seg * 7 + 1;
#pragma unroll
        for (int k = 0; k < 7; k++) v[k] = SAT2[rbase + k];
#pragma unroll
        for (int k = 1; k < 7; k++) { v[k].x += v[k - 1].x; v[k].y += v[k - 1].y; }
        tot2[seg * 56 + pos] = v[6];
    }
    __syncthreads();   // S3
    {
        float2 base = make_float2(0.f, 0.f);
        for (int s = 0; s < seg; s++) {
            float2 tv = tot2[s * 56 + pos];
            base.x += tv.x; base.y += tv.y;
        }
        const int rbase = (pos + 1) * 57 + seg * 7 + 1;
#pragma unroll
        for (int k = 0; k < 7; k++)
            SAT2[rbase + k] = make_float2(base.x + v[k].x, base.y + v[k].y);
    }
    __syncthreads();   // S4: full SAT + cst ready

    // ---- A3: gather 7 pixels x 2 channels -> pack A/B -> ABu + squeeze ----
    float asx = 0.f, asy = 0.f;
    {
        const int i = pos;
        const int j0 = seg * 7;
        const float xm = cst[6], xi = cst[7], xmxi = cst[8];
        const float d0 = cst[0], d1 = cst[1], d2 = cst[2], d3 = cst[3], d4 = cst[4], nd = cst[5];
        float C1x, C0x, C1y, C0y;
        {
            float g = gam[c0], be = bet[c0], bm = bnm[c0];
            float rsv = rsqrtf(bnv[c0] + 1e-3f);
            C1x = -(g * rsv) * (LOG2E * 0.1f);
            C0x = -(be - g * bm * rsv) * LOG2E;
            g = gam[c0 + 1]; be = bet[c0 + 1]; bm = bnm[c0 + 1];
            rsv = rsqrtf(bnv[c0 + 1] + 1e-3f);
            C1y = -(g * rsv) * (LOG2E * 0.1f);
            C0y = -(be - g * bm * rsv) * LOG2E;
        }

        auto mkU = [&](int hk) {
            ScaleU uu;
            int y1g = min(i + hk, 55) + 1;
            int y0g = max(i - hk + 1, 0);
            uu.rb1 = y1g * 57; uu.rb0 = y0g * 57;
            uu.xmch = xm * (float)(y1g - y0g);
            return uu;
        };
        const ScaleU u0 = mkU(1), u1 = mkU(2), u2 = mkU(4), u3 = mkU(8), u4 = mkU(16);

        auto meas = [&](int j, const ScaleU& uu, int hk) -> float2 {
            int x1g = min(j + hk, 55) + 1;
            int x0g = max(j - hk + 1, 0);
            float cw = (float)(x1g - x0g);
            float2 a = SAT2[uu.rb1 + x1g], bq = SAT2[uu.rb0 + x1g];
            float2 cq = SAT2[uu.rb1 + x0g], dq = SAT2[uu.rb0 + x0g];
            float sx = a.x - bq.x - cq.x + dq.x;
            float sy = a.y - bq.y - cq.y + dq.y;
            float tx = fmaf(-uu.xmch, cw, sx);
            float ty = fmaf(-uu.xmch, cw, sy);
            float2 r;
            r.x = __log2f(fmaxf(fmaf(tx, xi, 1e-7f), 1e-7f));
            r.y = __log2f(fmaxf(fmaf(ty, xi, 1e-7f), 1e-7f));
            return r;
        };

        const float2* xrow = (const float2*)(x + b * NPERB + i * 7168 + c0);
        uint2* abrow = (uint2*)(ABu + b * NPERB + i * 7168 + c0);
        // unroll-by-2 only; all values named (NO register arrays -> no scratch)
#pragma unroll 2
        for (int jj = 0; jj < 7; jj++) {
            int j = j0 + jj;
            float2 l0 = meas(j, u0, 1);
            float2 l1 = meas(j, u1, 2);
            float2 l2 = meas(j, u2, 4);
            float2 l3 = meas(j, u3, 8);
            float2 l4 = meas(j, u4, 16);
            float2 xv = xrow[j * 64];
            uint2 outw;
            {
                float w2 = -2.f * l0.x - l1.x + l3.x + 2.f * l4.x;
                asx += w2;
                float alphas = w2 * 0.1f;
                float mean = 0.2f * (l0.x + l1.x + l2.x + l3.x + l4.x);
                float a0 = l0.x - mean, a1 = l1.x - mean, a2 = l2.x - mean,
                      a3 = l3.x - mean, a4 = l4.x - mean;
                float na2  = a0 * a0 + a1 * a1 + a2 * a2 + a3 * a3 + a4 * a4;
                float adot = a0 * d0 + a1 * d1 + a2 * d2 + a3 * d3 + a4 * d4;
                float na = __builtin_amdgcn_sqrtf(na2);
                float cosv = (alphas * adot) *
                             __builtin_amdgcn_rcpf(na * fabsf(alphas) * nd + 1e-7f);
                float sim = 0.5f * (cosv + 1.f);
                float sbn = __builtin_amdgcn_rcpf(1.f + exp2f(C1x * w2 + C0x));
                float xs = fmaf(xv.x, xi, -xmxi);
                outw.x = __builtin_bit_cast(unsigned int,
                          __floats2half2_rn(sim * sbn, (1.f - sim) * xs));
            }
            {
                float w2 = -2.f * l0.y - l1.y + l3.y + 2.f * l4.y;
                asy += w2;
                float alphas = w2 * 0.1f;
                float mean = 0.2f * (l0.y + l1.y + l2.y + l3.y + l4.y);
                float a0 = l0.y - mean, a1 = l1.y - mean, a2 = l2.y - mean,
                      a3 = l3.y - mean, a4 = l4.y - mean;
                float na2  = a0 * a0 + a1 * a1 + a2 * a2 + a3 * a3 + a4 * a4;
                float adot = a0 * d0 + a1 * d1 + a2 * d2 + a3 * d3 + a4 * d4;
                float na = __builtin_amdgcn_sqrtf(na2);
                float cosv = (alphas * adot) *
                             __builtin_amdgcn_rcpf(na * fabsf(alphas) * nd + 1e-7f);
                float sim = 0.5f * (cosv + 1.f);
                float sbn = __builtin_amdgcn_rcpf(1.f + exp2f(C1y * w2 + C0y));
                float xs = fmaf(xv.y, xi, -xmxi);
                outw.y = __builtin_bit_cast(unsigned int,
                          __floats2half2_rn(sim * sbn, (1.f - sim) * xs));
            }
            abrow[j * 64] = outw;
        }
    }
    // squeeze: wave reduce both channels, then cross-wave via LDS
#pragma unroll
    for (int off = 32; off; off >>= 1) {
        asx += __shfl_down(asx, off);
        asy += __shfl_down(asy, off);
    }
    if ((t & 63) == 0) { wsum[(t >> 6) * 2] = asx; wsum[(t >> 6) * 2 + 1] = asy; }
    __syncthreads();
    if (t < 2) {
        float s = 0.f;
#pragma unroll
        for (int w = 0; w < 7; w++) s += wsum[w * 2 + t];
        atomicAdd(&sq[b * 128 + c0 + t], s * 0.1f);
    }
}

// ---------- K2: SE + mix (XCD-affine: b = p&15, ABu read is L2-local) ----------
__launch_bounds__(256)
__global__ void k_mix(const unsigned int* __restrict__ ABu, const float* __restrict__ sq,
                      const float* __restrict__ W1, const float* __restrict__ b1,
                      const float* __restrict__ W2, const float* __restrict__ b2,
                      float* __restrict__ out) {
    __shared__ float sqz[128];
    __shared__ float hidp[256];
    __shared__ float hid[16];
    __shared__ float exc[128];
    int p = blockIdx.x;
    int b = p & 15, chunk = p >> 4;
    int tid = threadIdx.x;
    if (tid < 128) sqz[tid] = sq[b * 128 + tid] * (1.f / 3136.f);
    __syncthreads();
    {   // W1 GEMV parallel: h = tid&15, c2 group = tid>>4 (8 c2 each)
        int h = tid & 15, g = tid >> 4;
        float acc = 0.f;
#pragma unroll
        for (int k = 0; k < 8; k++) {
            int c2 = g * 8 + k;
            acc += sqz[c2] * W1[c2 * 16 + h];
        }
        hidp[tid] = acc;
    }
    __syncthreads();
    if (tid < 16) {
        float acc = b1[tid];
#pragma unroll
        for (int g = 0; g < 16; g++) acc += hidp[g * 16 + tid];
        hid[tid] = fmaxf(acc, 0.f);
    }
    __syncthreads();
    if (tid < 128) {
        float acc = b2[tid];
#pragma unroll
        for (int h = 0; h < 16; h++) acc += hid[h] * W2[h * 128 + tid];
        exc[tid] = sigmoidf_fast(acc);
    }
    __syncthreads();
    const uint4* ab4 = (const uint4*)ABu + b * NQ4 + chunk * 784;
    float4* out4 = (float4*)out + b * NQ4 + chunk * 784;
    for (int q = tid; q < 784; q += 256) {
        int cb = ((chunk * 784 + q) & 31) << 2;
        uint4 u = ab4[q];
        float2 p0 = __half22float2(__builtin_bit_cast(__half2, u.x));
        float2 p1 = __half22float2(__builtin_bit_cast(__half2, u.y));
        float2 p2 = __half22float2(__builtin_bit_cast(__half2, u.z));
        float2 p3 = __half22float2(__builtin_bit_cast(__half2, u.w));
        out4[q] = make_float4(p0.x + p0.y * exc[cb],
                              p1.x + p1.y * exc[cb + 1],
                              p2.x + p2.y * exc[cb + 2],
                              p3.x + p3.y * exc[cb + 3]);
    }
}

extern "C" void kernel_launch(void* const* d_in, const int* in_sizes, int n_in,
                              void* d_out, int out_size, void* d_ws, size_t ws_size,
                              hipStream_t stream) {
    const float* x   = (const float*)d_in[0];
    const float* kap = (const float*)d_in[1];
    const float* W1  = (const float*)d_in[2];
    const float* b1  = (const float*)d_in[3];
    const float* W2  = (const float*)d_in[4];
    const float* b2  = (const float*)d_in[5];
    const float* gam = (const float*)d_in[6];
    const float* bet = (const float*)d_in[7];
    const float* bnm = (const float*)d_in[8];
    const float* bnv = (const float*)d_in[9];
    float* out = (float*)d_out;

    // ws: [sq 2048f][pmxp 1024f][pmnp 1024f][ABu NTOT u32]  (no memset needed:
    // sq zeroed by k_minmax chunk-0 blocks; pmxp/pmnp fully written per slot)
    float* sq   = (float*)d_ws;
    float* pmxp = sq + 2048;
    float* pmnp = pmxp + 1024;
    unsigned* ABu = (unsigned*)(pmnp + 1024);   // byte offset 16384, 16B aligned

    k_minmax<<<1024, 256, 0, stream>>>((const float4*)x, pmxp, pmnp, sq);
    k_satg<<<1024, 448, 0, stream>>>(x, kap, gam, bet, bnm, bnv, pmxp, pmnp, sq, ABu);
    k_mix<<<2048, 256, 0, stream>>>(ABu, sq, W1, b1, W2, b2, out);
}